// Round 2
// baseline (136.165 us; speedup 1.0000x reference)
//
#include <hip/hip_runtime.h>

#define NF    256   // IN_F
#define HD    256   // H*D
#define NH    4
#define DH    64
#define WINS  128   // WIN
#define HALFW 64
#define TOPK  32
#define GROWS 32    // rows per gemm block (4 waves x 8 rows)
#define NPB   4     // nodes per attn block (window-union sharing)

typedef float vfloat4 __attribute__((ext_vector_type(4)));  // nt-store capable

// 16-lane sum via DPP (all-VALU, zero DS ops). After the 4 adds every lane
// in each 16-lane group holds the group sum.
__device__ __forceinline__ float dpp_add16(float v) {
    int x;
    x = __builtin_amdgcn_update_dpp(0, __float_as_int(v), 0xB1, 0xF, 0xF, true);  // quad_perm xor1
    v += __int_as_float(x);
    x = __builtin_amdgcn_update_dpp(0, __float_as_int(v), 0x4E, 0xF, 0xF, true);  // quad_perm xor2
    v += __int_as_float(x);
    x = __builtin_amdgcn_update_dpp(0, __float_as_int(v), 0x124, 0xF, 0xF, true); // row_ror:4
    v += __int_as_float(x);
    x = __builtin_amdgcn_update_dpp(0, __float_as_int(v), 0x128, 0xF, 0xF, true); // row_ror:8
    v += __int_as_float(x);
    return v;
}

// ------------- fused Q/K projection: X[n,256] @ W[256,256] + b -------------
// R1: col-split (gridDim.z picks a 128-col half, float2 per lane) for
// 2 waves/SIMD. Bit-exact; unchanged this round.
__global__ __launch_bounds__(256, 2) void qk_gemm_kernel(
    const float* __restrict__ X,
    const float* __restrict__ Wq, const float* __restrict__ bq,
    const float* __restrict__ Wk, const float* __restrict__ bk,
    float* __restrict__ Qb, float* __restrict__ Kb, int n)
{
    const int t    = threadIdx.x;
    const int wave = t >> 6;
    const int lane = t & 63;
    const bool isK = (blockIdx.y != 0);
    const int half = blockIdx.z;
    const float* W   = isK ? Wk : Wq;
    const float* bia = isK ? bk : bq;
    float*       Out = isK ? Kb : Qb;

    const int gx = gridDim.x;
    int bswz = blockIdx.x;
    if ((gx & 7) == 0) {
        int chunk = gx >> 3;
        bswz = (blockIdx.x & 7) * chunk + (blockIdx.x >> 3);
    }
    const int r0  = bswz * GROWS + wave * 8;
    const int r0s = __builtin_amdgcn_readfirstlane(r0);
    const float* Xs = X + (size_t)r0s * NF;        // scalar base -> s_load

    const int c0 = half * 128 + 2 * lane;          // 2 cols per lane

    float2 acc[8];
#pragma unroll
    for (int r = 0; r < 8; ++r) acc[r] = make_float2(0.f, 0.f);

    float2 wA[8], wB[8];
    const float* Wl = W + c0;

#pragma unroll
    for (int u = 0; u < 8; ++u)                     // prologue: group 0
        wA[u] = *(const float2*)(Wl + (size_t)u * HD);

    for (int k = 0; k < NF; k += 16) {
        if (k + 8 < NF) {                           // prefetch group g+1
#pragma unroll
            for (int u = 0; u < 8; ++u)
                wB[u] = *(const float2*)(Wl + (size_t)(k + 8 + u) * HD);
        }
#pragma unroll
        for (int u = 0; u < 8; ++u) {
#pragma unroll
            for (int r = 0; r < 8; ++r) {
                float xk = Xs[r * NF + k + u];      // SGPR broadcast
                acc[r].x += xk * wA[u].x;
                acc[r].y += xk * wA[u].y;
            }
        }
        if (k + 16 < NF) {                          // prefetch group g+2
#pragma unroll
            for (int u = 0; u < 8; ++u)
                wA[u] = *(const float2*)(Wl + (size_t)(k + 16 + u) * HD);
        }
#pragma unroll
        for (int u = 0; u < 8; ++u) {
#pragma unroll
            for (int r = 0; r < 8; ++r) {
                float xk = Xs[r * NF + k + 8 + u];  // SGPR broadcast
                acc[r].x += xk * wB[u].x;
                acc[r].y += xk * wB[u].y;
            }
        }
    }

    const float2 bv = *(const float2*)(bia + c0);
#pragma unroll
    for (int r = 0; r < 8; ++r) {
        acc[r].x += bv.x; acc[r].y += bv.y;
        *(float2*)(Out + (size_t)(r0 + r) * HD + c0) = acc[r];  // coalesced 8B
    }
}

// ---- windowed attention + top-32, NPB=4 consecutive nodes per block ----
// Adjacent nodes share 127/128 of their K windows: load the union window
// (<=131 rows) ONCE, compute all 4 nodes' scores per loaded row.
// K L2 traffic drops 4x (537 MB -> 134 MB); all arithmetic bit-identical
// to the verified single-node kernel (same dot expr, DPP tree, softmax,
// mean order, stable top-k count).
__global__ __launch_bounds__(256) void attn_topk_kernel(
    const float* __restrict__ Q,
    const float* __restrict__ K,
    const int* __restrict__ nnpg, int n_graphs,
    const int* __restrict__ nrel,
    float* __restrict__ out, int n)
{
    const int t    = threadIdx.x;
    const int wave = t >> 6;
    const int lane = t & 63;

    int b = blockIdx.x;
    const int nb = gridDim.x;
    if ((nb & 7) == 0) {                      // bijective XCD swizzle
        int chunk = nb >> 3;
        b = (blockIdx.x & 7) * chunk + (blockIdx.x >> 3);
    }
    const int i0 = b * NPB;

    __shared__ float sc[NH][NPB][WINS];       // scores, then probs in-place
    __shared__ float attnv[NPB][WINS];
    __shared__ float slotval[NPB][WINS];

    // per-node segment bounds: tile(nnpg, R) -> cumsum -> searchsorted(right)
    const int R = nrel[0];
    const int total = n_graphs * R;
    int startv[NPB], endv[NPB];
#pragma unroll
    for (int nn = 0; nn < NPB; ++nn) {
        const int i = i0 + nn;
        int cs = 0, s0 = 0, e0 = n;
        for (int e = 0; e < total; ++e) {
            int sz = nnpg[e % n_graphs];
            int nc = cs + sz;
            if (i < nc) { s0 = cs; e0 = nc; break; }
            cs = nc;
        }
        startv[nn] = max(s0, i - HALFW);
        endv[nn]   = min(e0, i + HALFW);
    }
    const int u0    = startv[0];              // start[] nondecreasing
    const int urows = endv[NPB - 1] - u0;     // union window, <= 131 rows

    // zero-init scores (padded slots must contribute exactly 0 to softmax)
    {
        float4* scv = (float4*)&sc[0][0][0];
        for (int idx = t; idx < NH * NPB * WINS / 4; idx += 256)
            scv[idx] = make_float4(0.f, 0.f, 0.f, 0.f);
    }

    // q fragments: this lane's 4 dims of head (lane>>4), for each node
    float4 q4[NPB];
#pragma unroll
    for (int nn = 0; nn < NPB; ++nn)
        q4[nn] = *(const float4*)(Q + (size_t)(i0 + nn) * HD + lane * 4);

    __syncthreads();                          // init visible before A stores

    // ---- phase A: union rows round-robin over waves; DPP 16-lane sums ----
#pragma unroll 4
    for (int r = wave; r < urows; r += 4) {
        const int row = u0 + r;
        const float4 k4 = *(const float4*)(K + (size_t)row * HD + lane * 4);
#pragma unroll
        for (int nn = 0; nn < NPB; ++nn) {
            float v = q4[nn].x * k4.x + q4[nn].y * k4.y
                    + q4[nn].z * k4.z + q4[nn].w * k4.w;
            v = dpp_add16(v);                 // all-VALU 16-lane sum
            const int rel = row - startv[nn];
            if ((lane & 15) == 0 &&
                (unsigned)rel < (unsigned)(endv[nn] - startv[nn]))
                sc[lane >> 4][nn][rel] = v * 0.25f;  // /sqrt(64)/tau
        }
    }

    // ---- overlapped zero-write: all float4s outside each node's window ----
    const int n4 = n >> 2;
    const vfloat4 z4 = {0.f, 0.f, 0.f, 0.f};
#pragma unroll
    for (int nn = 0; nn < NPB; ++nn) {
        vfloat4* orow = (vfloat4*)(out + (size_t)(i0 + nn) * n);
        const int lo4 = startv[nn] >> 2;
        const int hi4 = (endv[nn] - 1) >> 2;  // inclusive
        for (int c4 = t; c4 < n4; c4 += 256) {
            if (c4 >= lo4 && c4 <= hi4) continue;
            __builtin_nontemporal_store(z4, &orow[c4]);
        }
    }
    __syncthreads();

    // ---- per-head softmax (wave w = head w), in-place over sc ----
#pragma unroll
    for (int nn = 0; nn < NPB; ++nn) {
        float v0 = sc[wave][nn][lane], v1 = sc[wave][nn][lane + 64];
        float mx = fmaxf(v0, v1);
#pragma unroll
        for (int off = 32; off > 0; off >>= 1) mx = fmaxf(mx, __shfl_xor(mx, off));
        float e0 = expf(v0 - mx), e1 = expf(v1 - mx);
        float sm = e0 + e1;
#pragma unroll
        for (int off = 32; off > 0; off >>= 1) sm += __shfl_xor(sm, off);
        sc[wave][nn][lane]      = e0 / sm;
        sc[wave][nn][lane + 64] = e1 / sm;
    }
    __syncthreads();

    // ---- mean over heads; invalid slots excluded from top-k ----
#pragma unroll
    for (int hh = 0; hh < 2; ++hh) {
        const int idx = t + hh * 256;         // 0..511 = 4 nodes x 128 slots
        const int nn = idx >> 7, s = idx & 127;
        float a = 0.25f * (sc[0][nn][s] + sc[1][nn][s]
                         + sc[2][nn][s] + sc[3][nn][s]);
        attnv[nn][s] = (s < endv[nn] - startv[nn]) ? a : -1.0f;
    }
    __syncthreads();

    // ---- stable top-32 rank count (lower index wins ties, lax.top_k) ----
#pragma unroll
    for (int hh = 0; hh < 2; ++hh) {
        const int idx = t + hh * 256;
        const int nn = idx >> 7, s = idx & 127;
        const float v = attnv[nn][s];
        int cnt = 0;
#pragma unroll
        for (int j4 = 0; j4 < WINS / 4; ++j4) {
            float4 a4 = *(const float4*)&attnv[nn][j4 * 4];
            int jb = j4 * 4;
            cnt += (a4.x > v) || (a4.x == v && (jb + 0) < s);
            cnt += (a4.y > v) || (a4.y == v && (jb + 1) < s);
            cnt += (a4.z > v) || (a4.z == v && (jb + 2) < s);
            cnt += (a4.w > v) || (a4.w == v && (jb + 3) < s);
        }
        slotval[nn][s] =
            (s < endv[nn] - startv[nn] && cnt < TOPK) ? 1.0f : 0.0f;
    }
    __syncthreads();

    // ---- final pass: wave w writes node w's <=34 window float4s ----
    {
        const int nn = wave;
        vfloat4* orow = (vfloat4*)(out + (size_t)(i0 + nn) * n);
        const int st = startv[nn];
        const int lo4 = st >> 2;
        const int hi4 = (endv[nn] - 1) >> 2;
        const int c4 = lo4 + lane;
        if (c4 <= hi4) {
            const int c = c4 << 2;
            const int o0 = c - st, o1 = o0 + 1, o2 = o0 + 2, o3 = o0 + 3;
            vfloat4 v4;
            v4.x = (o0 >= 0 && o0 < WINS) ? slotval[nn][o0] : 0.f;
            v4.y = (o1 >= 0 && o1 < WINS) ? slotval[nn][o1] : 0.f;
            v4.z = (o2 >= 0 && o2 < WINS) ? slotval[nn][o2] : 0.f;
            v4.w = (o3 >= 0 && o3 < WINS) ? slotval[nn][o3] : 0.f;
            __builtin_nontemporal_store(v4, &orow[c4]);
        }
    }
}

extern "C" void kernel_launch(void* const* d_in, const int* in_sizes, int n_in,
                              void* d_out, int out_size, void* d_ws, size_t ws_size,
                              hipStream_t stream)
{
    const float* X  = (const float*)d_in[0];
    const float* Wq = (const float*)d_in[1];
    const float* bq = (const float*)d_in[2];
    const float* Wk = (const float*)d_in[3];
    const float* bk = (const float*)d_in[4];
    const int* nnpg = (const int*)d_in[5];
    const int* nrel = (const int*)d_in[6];

    const int n = in_sizes[0] / NF;
    const int n_graphs = in_sizes[5];

    float* Qb = (float*)d_ws;                 // [n][256]
    float* Kb = Qb + (size_t)n * HD;          // [n][256]
    float* out = (float*)d_out;

    dim3 gg(n / GROWS, 2, 2);                 // z: 128-col half
    qk_gemm_kernel<<<gg, 256, 0, stream>>>(X, Wq, bq, Wk, bk, Qb, Kb, n);

    attn_topk_kernel<<<n / NPB, 256, 0, stream>>>(Qb, Kb, nnpg, n_graphs, nrel,
                                                  out, n);
}